// Round 4
// baseline (332.382 us; speedup 1.0000x reference)
//
#include <hip/hip_runtime.h>
#include <hip/hip_bf16.h>

#define N_NODES 100000
#define N_EDGES 800000
#define D 64
#define SCAN_B 256
#define NB1 ((N_NODES + SCAN_B - 1) / SCAN_B)   // 391 blocks
#define FILL_BLOCKS (N_EDGES / 256)             // 3125, exact
#define INIT_BLOCKS (N_NODES * D / 256)         // 25000, exact

// bf16 helpers: storage-only bf16 (embeds); all math in fp32.
__device__ __forceinline__ unsigned short f2bf(float f) {
    union { float f; unsigned u; } v; v.f = f;
    unsigned r = v.u + 0x7fffu + ((v.u >> 16) & 1u);   // round-to-nearest-even
    return (unsigned short)(r >> 16);
}
__device__ __forceinline__ float bf2f(unsigned short u) {
    return __uint_as_float(((unsigned)u) << 16);
}
__device__ __forceinline__ void acc_bf8(float acc[8], uint4 u) {
    acc[0] += __uint_as_float(u.x << 16);
    acc[1] += __uint_as_float(u.x & 0xffff0000u);
    acc[2] += __uint_as_float(u.y << 16);
    acc[3] += __uint_as_float(u.y & 0xffff0000u);
    acc[4] += __uint_as_float(u.z << 16);
    acc[5] += __uint_as_float(u.z & 0xffff0000u);
    acc[6] += __uint_as_float(u.w << 16);
    acc[7] += __uint_as_float(u.w & 0xffff0000u);
}
__device__ __forceinline__ unsigned pack2bf(float a, float b) {
    return (unsigned)f2bf(a) | ((unsigned)f2bf(b) << 16);
}

// ---------------------------------------------------------------------------
// hist + rank: deg[dst]++, rank[e] = arrival order of edge e at its dst.
// NOTE (R2 post-mortem): do NOT replace with cursor atomics inside the fill —
// the dependent atomic-return -> scattered-store chain cost +40 us and +50 MB
// of writebacks. Rank-based two-pass is the measured winner.
__global__ __launch_bounds__(256) void hist_rank_kernel(
        const int2* __restrict__ edges,
        int* __restrict__ deg,
        int* __restrict__ rank) {
    int t = blockIdx.x * 256 + threadIdx.x;
    int2 e = edges[t];                      // grid exact: 3125*256 == N_EDGES
    rank[t] = atomicAdd(&deg[e.y], 1);
}

// ---------------------------------------------------------------------------
// scan1: block-local exclusive scan over deg -> row_ptr, emit block totals.
__global__ void scan1_kernel(const int* __restrict__ deg,
                             int* __restrict__ row_ptr,
                             int* __restrict__ bsum) {
    __shared__ int tmp[SCAN_B];
    int t = threadIdx.x;
    int i = blockIdx.x * SCAN_B + t;
    int v = (i < N_NODES) ? deg[i] : 0;
    tmp[t] = v;
    __syncthreads();
#pragma unroll
    for (int off = 1; off < SCAN_B; off <<= 1) {
        int a = (t >= off) ? tmp[t - off] : 0;
        __syncthreads();
        tmp[t] += a;
        __syncthreads();
    }
    if (i < N_NODES) row_ptr[i] = tmp[t] - v;   // exclusive
    if (t == SCAN_B - 1) bsum[blockIdx.x] = tmp[t];
}

// scan2+scan3 merged: each block reduce-sums bsum[0..blockIdx-1] (391 ints)
// and adds it to its 256 row_ptr entries.
__global__ void scan23_kernel(int* __restrict__ row_ptr,
                              const int* __restrict__ bsum) {
    __shared__ int red[SCAN_B];
    int t = threadIdx.x;
    int partial = 0;
    if (t < blockIdx.x && t < NB1) partial += bsum[t];
    int t2 = t + 256;
    if (t2 < blockIdx.x && t2 < NB1) partial += bsum[t2];
    red[t] = partial;
    __syncthreads();
#pragma unroll
    for (int off = 128; off > 0; off >>= 1) {
        if (t < off) red[t] += red[t + off];
        __syncthreads();
    }
    int boff = red[0];
    int i = blockIdx.x * SCAN_B + t;
    if (i < N_NODES) row_ptr[i] += boff;
    if (i == 0) row_ptr[N_NODES] = N_EDGES;
}

// ---------------------------------------------------------------------------
// Fused dispatch: blocks [0, FILL_BLOCKS) scatter CSR cols (atomic-free via
// rank); blocks [FILL_BLOCKS, +INIT_BLOCKS) compute initial embeddings (bf16).
__global__ __launch_bounds__(256) void fill_init_kernel(
        const int2* __restrict__ edges,
        const int* __restrict__ rank,
        const int* __restrict__ rowp,
        int* __restrict__ col,
        const int* __restrict__ nodes,
        const float* __restrict__ features,
        const float* __restrict__ node_emb,
        const float* __restrict__ feat_W,
        const float* __restrict__ feat_b,
        unsigned short* __restrict__ embeds) {
    if (blockIdx.x < FILL_BLOCKS) {
        int t = blockIdx.x * 256 + threadIdx.x;
        int2 e = edges[t];
        col[rowp[e.y] + rank[t]] = e.x;
    } else {
        int tid = (blockIdx.x - FILL_BLOCKS) * 256 + threadIdx.x;
        int node = tid >> 6;
        int d = tid & 63;
        float acc = feat_b[d];
        const float* f = features + (size_t)node * 10;
        const float* w = feat_W + (size_t)d * 10;
#pragma unroll
        for (int j = 0; j < 10; ++j) acc += f[j] * w[j];
        embeds[tid] = f2bf(node_emb[(size_t)nodes[node] * D + d] + acc);
    }
}

// ---------------------------------------------------------------------------
// FUSED gather + per-node conv (keeps R0's 1-wave-per-node concurrency;
// R1's failure was fusing gather into the conv's block-tile — the inverse).
//
// Phase 0 (once per block): stage fp32 W into LDS with swizzled layout
//   Wl[(j*64 + g*8 + c)*8 + i] = W[g*8+j][c*8+i]
// so that in the conv phase lane L=(g,c) reads its 8x8 W block as two b128s
// at byte offset (j*64+L)*32: lane-stride 32 B -> dense 8-pass, conflict-free.
// One __syncthreads() here; after it every wave is fully independent.
//
// Phase A (gather, unchanged structure): x = emb[node] + sum emb[src].
// 8 groups x 8 lanes; group g loads src row (r*8+g) as uint4 (16 B/lane,
// 128 B/row coalesced); xor-reduce over g-bits (8,16,32) -> lane (g,c)
// holds fp32 x-chunk c (replicated over g).
//
// Phase B (conv, in-register): y[g*8+j] partial = dot8(x_chunk_c, W-block),
// xor-reduce over c-bits (1,2,4) -> all lanes of group g hold y[g*8..+7].
// +bias (LDS), relu.
//   !SCORE: lanes c==0 pack 8 bf16 -> uint4, write seg g of the row.
//   SCORE:  per-lane dot/n2/pn over its 8 dims, xor-reduce over g-bits,
//           lane 0 writes cosine score. No y materialization at all.
//
// Removes per iteration: conv dispatch, 12.8 MB x-read, 12.8 MB y-write glue
// (iter2). VGPR grows (y[8] + W temps): launch_bounds(256,6) = 85-reg cap,
// no spill; accepts 6 waves/SIMD vs gather-only's 8.
template <bool SCORE>
__global__ __launch_bounds__(256, 6) void gatherconv_kernel(
        const unsigned short* __restrict__ emb_in,
        const int* __restrict__ rowp,
        const int* __restrict__ col,
        const float* __restrict__ W,
        const float* __restrict__ b,
        const float* __restrict__ pattern_emb,
        const int* __restrict__ pattern_id,
        unsigned short* __restrict__ emb_out,
        float* __restrict__ score_out) {
    __shared__ float Wl[4096];      // 16 KB swizzled fp32 W
    __shared__ float bl[64];
    __shared__ float ps[64];

    int t = threadIdx.x;

    // ---- Phase 0: stage W (4 x float4 per thread, coalesced) ----
#pragma unroll
    for (int q = 0; q < 4; ++q) {
        int v = t + 256 * q;                  // float4 index 0..1023
        float4 w4 = ((const float4*)W)[v];
        int d  = v >> 4;                      // W row 0..63
        int k4 = v & 15;                      // float4 within row
        int c  = k4 >> 1;
        int i0 = (k4 & 1) * 4;
        int slot = ((d & 7) * 64) + ((d >> 3) * 8) + c;
        *((float4*)&Wl[slot * 8 + i0]) = w4;
    }
    if (t < 64) bl[t] = b[t];
    if (SCORE && t < 64) ps[t] = pattern_emb[(size_t)pattern_id[0] * D + t];
    __syncthreads();                          // only barrier; waves free after

    int lane = t & 63;
    int wv   = t >> 6;
    int node = blockIdx.x * 4 + wv;           // grid = 25000, exact
    int g = lane >> 3;                        // row-group / output-group 0..7
    int c = lane & 7;                         // uint4 chunk / k-chunk 0..7

    // ---- Phase A: gather ----
    int start = rowp[node];
    int end   = rowp[node + 1];

    float acc[8];
#pragma unroll
    for (int j = 0; j < 8; ++j) acc[j] = 0.f;
    if (g == 0) {                             // self term, counted once
        uint4 u = ((const uint4*)(emb_in + (size_t)node * D))[c];
        acc_bf8(acc, u);
    }

    for (int base = start; base < end; base += 32) {
        int nb = end - base; if (nb > 32) nb = 32;
        int idx = (lane < nb) ? col[base + lane] : 0;   // lanes 0..31, coalesced
#pragma unroll
        for (int r = 0; r < 4; ++r) {
            int s = r * 8 + g;                          // 0..31
            int src = __shfl(idx, s, 64);               // all lanes active
            if (s < nb) {                               // per-lane predication
                uint4 u = ((const uint4*)(emb_in + (size_t)src * D))[c];
                acc_bf8(acc, u);
            }
        }
    }
    // combine the 8 group partials (xor 8, 16, 32): lane (g,c) -> x[8c..8c+7]
#pragma unroll
    for (int m = 8; m <= 32; m <<= 1) {
#pragma unroll
        for (int j = 0; j < 8; ++j) acc[j] += __shfl_xor(acc[j], m, 64);
    }

    // ---- Phase B: per-node conv y = relu(x @ W^T + b) ----
    float y[8];
#pragma unroll
    for (int j = 0; j < 8; ++j) {
        const float4* wp = (const float4*)&Wl[(j * 64 + lane) * 8];
        float4 w0 = wp[0], w1 = wp[1];
        y[j] = acc[0] * w0.x + acc[1] * w0.y + acc[2] * w0.z + acc[3] * w0.w
             + acc[4] * w1.x + acc[5] * w1.y + acc[6] * w1.z + acc[7] * w1.w;
    }
#pragma unroll
    for (int m = 1; m <= 4; m <<= 1) {        // reduce over k-chunks (c bits)
#pragma unroll
        for (int j = 0; j < 8; ++j) y[j] += __shfl_xor(y[j], m, 64);
    }
#pragma unroll
    for (int j = 0; j < 8; ++j) y[j] = fmaxf(y[j] + bl[g * 8 + j], 0.f);

    if (!SCORE) {
        if (c == 0) {                         // 8 lanes x 16 B = 128 B bf16 row
            uint4 p;
            p.x = pack2bf(y[0], y[1]);
            p.y = pack2bf(y[2], y[3]);
            p.z = pack2bf(y[4], y[5]);
            p.w = pack2bf(y[6], y[7]);
            ((uint4*)(emb_out + (size_t)node * D))[g] = p;
        }
    } else {
        float dot = 0.f, n2 = 0.f, pn = 0.f;
#pragma unroll
        for (int j = 0; j < 8; ++j) {
            float pk = ps[g * 8 + j];
            dot += y[j] * pk; n2 += y[j] * y[j]; pn += pk * pk;
        }
#pragma unroll
        for (int m = 8; m <= 32; m <<= 1) {   // reduce over output-groups (g bits)
            dot += __shfl_xor(dot, m, 64);
            n2  += __shfl_xor(n2,  m, 64);
            pn  += __shfl_xor(pn,  m, 64);
        }
        if (lane == 0)
            score_out[node] = dot / (fmaxf(sqrtf(n2), 1e-8f) * fmaxf(sqrtf(pn), 1e-8f));
    }
}

// ---------------------------------------------------------------------------
// Fallback path (atomic scatter, full fp32) if ws too small for CSR arrays.
__global__ void init_embeds_kernel(const int* __restrict__ nodes,
                                   const float* __restrict__ features,
                                   const float* __restrict__ node_emb,
                                   const float* __restrict__ feat_W,
                                   const float* __restrict__ feat_b,
                                   float* __restrict__ embeds) {
    int tid = blockIdx.x * blockDim.x + threadIdx.x;
    if (tid >= N_NODES * D) return;
    int node = tid >> 6;
    int d = tid & 63;
    float acc = feat_b[d];
    const float* f = features + (size_t)node * 10;
    const float* w = feat_W + (size_t)d * 10;
#pragma unroll
    for (int j = 0; j < 10; ++j) acc += f[j] * w[j];
    embeds[tid] = node_emb[(size_t)nodes[node] * D + d] + acc;
}

__global__ void scatter_add_kernel(const int* __restrict__ edges,
                                   const float* __restrict__ embeds,
                                   float* __restrict__ agg) {
    int tid = blockIdx.x * blockDim.x + threadIdx.x;
    int edge = tid >> 6;
    int lane = tid & 63;
    if (edge >= N_EDGES) return;
    int src = edges[2 * edge + 0];
    int dst = edges[2 * edge + 1];
    atomicAdd(&agg[(size_t)dst * D + lane], embeds[(size_t)src * D + lane]);
}

__global__ void conv_inplace_kernel(const float* __restrict__ agg,
                                    const float* __restrict__ W,
                                    const float* __restrict__ b,
                                    float* __restrict__ embeds) {
    __shared__ float Ws[D * 65];
    __shared__ float xs[4][D];
    for (int i = threadIdx.x; i < D * D; i += blockDim.x) {
        int d = i >> 6, k = i & 63;
        Ws[d * 65 + k] = W[i];
    }
    __syncthreads();
    int lane_d = threadIdx.x & 63;
    int local_n = threadIdx.x >> 6;
    float bias = b[lane_d];
    const int n_chunks = (N_NODES + 3) / 4;
    for (int chunk = blockIdx.x; chunk < n_chunks; chunk += gridDim.x) {
        int node = chunk * 4 + local_n;
        if (node < N_NODES) {
            size_t base = (size_t)node * D + lane_d;
            xs[local_n][lane_d] = embeds[base] + agg[base];
        }
        __syncthreads();
        if (node < N_NODES) {
            float acc = bias;
#pragma unroll
            for (int k = 0; k < D; ++k) acc += xs[local_n][k] * Ws[lane_d * 65 + k];
            embeds[(size_t)node * D + lane_d] = fmaxf(acc, 0.0f);
        }
        __syncthreads();
    }
}

__global__ void final_score_kernel(const float* __restrict__ embeds,
                                   const float* __restrict__ pattern_emb,
                                   const int* __restrict__ pattern_id,
                                   float* __restrict__ out) {
    int lane = threadIdx.x & 63;
    int wave = threadIdx.x >> 6;
    int node = blockIdx.x * 4 + wave;
    int pid = pattern_id[0];
    float p = pattern_emb[(size_t)pid * D + lane];
    float pn = p * p;
#pragma unroll
    for (int m = 32; m > 0; m >>= 1) pn += __shfl_xor(pn, m, 64);
    if (node < N_NODES) {
        float e = embeds[(size_t)node * D + lane];
        float dot = e * p;
        float n2 = e * e;
#pragma unroll
        for (int m = 32; m > 0; m >>= 1) {
            dot += __shfl_xor(dot, m, 64);
            n2  += __shfl_xor(n2, m, 64);
        }
        if (lane == 0) {
            float denom = fmaxf(sqrtf(n2), 1e-8f) * fmaxf(sqrtf(pn), 1e-8f);
            out[node] = dot / denom;
        }
    }
}

// ---------------------------------------------------------------------------
extern "C" void kernel_launch(void* const* d_in, const int* in_sizes, int n_in,
                              void* d_out, int out_size, void* d_ws, size_t ws_size,
                              hipStream_t stream) {
    const int*   nodes       = (const int*)d_in[0];
    const int*   edges       = (const int*)d_in[1];
    const float* features    = (const float*)d_in[2];
    const float* node_emb    = (const float*)d_in[3];
    const float* feat_W      = (const float*)d_in[4];
    const float* feat_b      = (const float*)d_in[5];
    const float* conv1_W     = (const float*)d_in[6];
    const float* conv1_b     = (const float*)d_in[7];
    const float* pattern_emb = (const float*)d_in[8];
    const int*   pattern_id  = (const int*)d_in[9];
    float* out = (float*)d_out;

    const size_t emb_f32_bytes = (size_t)N_NODES * D * sizeof(float);   // 25.6 MB
    const size_t emb_bf_bytes  = (size_t)N_NODES * D * 2;               // 12.8 MB
    auto align256 = [](size_t x) { return (x + 255) & ~(size_t)255; };

    size_t o_embA = 0;
    size_t o_embB = o_embA + align256(emb_bf_bytes);
    size_t o_col  = o_embB + align256(emb_bf_bytes);
    size_t o_rank = o_col  + align256((size_t)N_EDGES * 4);
    size_t o_row  = o_rank + align256((size_t)N_EDGES * 4);
    size_t o_deg  = o_row  + align256((size_t)(N_NODES + 1) * 4);
    size_t o_bsum = o_deg  + align256((size_t)N_NODES * 4);
    size_t need   = o_bsum + align256((size_t)NB1 * 4);

    char* ws = (char*)d_ws;

    if (ws_size >= need) {
        unsigned short* embA = (unsigned short*)(ws + o_embA);
        unsigned short* embB = (unsigned short*)(ws + o_embB);
        int*   col  = (int*)(ws + o_col);
        int*   rank = (int*)(ws + o_rank);
        int*   rowp = (int*)(ws + o_row);
        int*   deg  = (int*)(ws + o_deg);
        int*   bsum = (int*)(ws + o_bsum);

        hipMemsetAsync(deg, 0, (size_t)N_NODES * 4, stream);
        hist_rank_kernel<<<FILL_BLOCKS, 256, 0, stream>>>((const int2*)edges, deg, rank);
        scan1_kernel<<<NB1, SCAN_B, 0, stream>>>(deg, rowp, bsum);
        scan23_kernel<<<NB1, SCAN_B, 0, stream>>>(rowp, bsum);
        fill_init_kernel<<<FILL_BLOCKS + INIT_BLOCKS, 256, 0, stream>>>(
            (const int2*)edges, rank, rowp, col,
            nodes, features, node_emb, feat_W, feat_b, embA);

        // iter 1: fused gather+conv -> embB (bf16)
        gatherconv_kernel<false><<<N_NODES / 4, 256, 0, stream>>>(
            embA, rowp, col, conv1_W, conv1_b, pattern_emb, pattern_id, embB, nullptr);
        // iter 2: fused gather+conv+cosine score -> out (no y materialization)
        gatherconv_kernel<true><<<N_NODES / 4, 256, 0, stream>>>(
            embB, rowp, col, conv1_W, conv1_b, pattern_emb, pattern_id, nullptr, out);
    } else {
        float* embeds = (float*)ws;
        float* agg = (float*)(ws + align256(emb_f32_bytes));
        init_embeds_kernel<<<(N_NODES * D + 255) / 256, 256, 0, stream>>>(
            nodes, features, node_emb, feat_W, feat_b, embeds);
        for (int it = 0; it < 2; ++it) {
            hipMemsetAsync(agg, 0, emb_f32_bytes, stream);
            long long total = (long long)N_EDGES * 64;
            scatter_add_kernel<<<(int)((total + 255) / 256), 256, 0, stream>>>(edges, embeds, agg);
            conv_inplace_kernel<<<2048, 256, 0, stream>>>(agg, conv1_W, conv1_b, embeds);
        }
        final_score_kernel<<<(N_NODES + 3) / 4, 256, 0, stream>>>(
            embeds, pattern_emb, pattern_id, out);
    }
}

// Round 5
// 318.929 us; speedup vs baseline: 1.0422x; 1.0422x over previous
//
#include <hip/hip_runtime.h>
#include <hip/hip_bf16.h>

#define N_NODES 100000
#define N_EDGES 800000
#define D 64
#define SCAN_B 256
#define NB1 ((N_NODES + SCAN_B - 1) / SCAN_B)   // 391 blocks
#define FILL_BLOCKS (N_EDGES / 256)             // 3125, exact
#define INIT_BLOCKS (N_NODES * D / 256)         // 25000, exact

// bf16 helpers: storage-only bf16 (embeds); all math in fp32.
__device__ __forceinline__ unsigned short f2bf(float f) {
    union { float f; unsigned u; } v; v.f = f;
    unsigned r = v.u + 0x7fffu + ((v.u >> 16) & 1u);   // round-to-nearest-even
    return (unsigned short)(r >> 16);
}
__device__ __forceinline__ float bf2f(unsigned short u) {
    return __uint_as_float(((unsigned)u) << 16);
}
__device__ __forceinline__ void acc_bf8(float acc[8], uint4 u) {
    acc[0] += __uint_as_float(u.x << 16);
    acc[1] += __uint_as_float(u.x & 0xffff0000u);
    acc[2] += __uint_as_float(u.y << 16);
    acc[3] += __uint_as_float(u.y & 0xffff0000u);
    acc[4] += __uint_as_float(u.z << 16);
    acc[5] += __uint_as_float(u.z & 0xffff0000u);
    acc[6] += __uint_as_float(u.w << 16);
    acc[7] += __uint_as_float(u.w & 0xffff0000u);
}
__device__ __forceinline__ unsigned pack2bf(float a, float b) {
    return (unsigned)f2bf(a) | ((unsigned)f2bf(b) << 16);
}

// ---------------------------------------------------------------------------
// hist + rank: deg[dst]++, rank[e] = arrival order of edge e at its dst.
// NOTE (R2): cursor-atomic fill cost +40 us / +50 MB writebacks. Keep this.
__global__ __launch_bounds__(256) void hist_rank_kernel(
        const int2* __restrict__ edges,
        int* __restrict__ deg,
        int* __restrict__ rank) {
    int t = blockIdx.x * 256 + threadIdx.x;
    int2 e = edges[t];                      // grid exact: 3125*256 == N_EDGES
    rank[t] = atomicAdd(&deg[e.y], 1);
}

// ---------------------------------------------------------------------------
// scan1: block-local exclusive scan over deg -> row_ptr, emit block totals.
__global__ void scan1_kernel(const int* __restrict__ deg,
                             int* __restrict__ row_ptr,
                             int* __restrict__ bsum) {
    __shared__ int tmp[SCAN_B];
    int t = threadIdx.x;
    int i = blockIdx.x * SCAN_B + t;
    int v = (i < N_NODES) ? deg[i] : 0;
    tmp[t] = v;
    __syncthreads();
#pragma unroll
    for (int off = 1; off < SCAN_B; off <<= 1) {
        int a = (t >= off) ? tmp[t - off] : 0;
        __syncthreads();
        tmp[t] += a;
        __syncthreads();
    }
    if (i < N_NODES) row_ptr[i] = tmp[t] - v;   // exclusive
    if (t == SCAN_B - 1) bsum[blockIdx.x] = tmp[t];
}

// scan2+scan3 merged: each block reduce-sums bsum[0..blockIdx-1] (391 ints)
// and adds it to its 256 row_ptr entries.
__global__ void scan23_kernel(int* __restrict__ row_ptr,
                              const int* __restrict__ bsum) {
    __shared__ int red[SCAN_B];
    int t = threadIdx.x;
    int partial = 0;
    if (t < blockIdx.x && t < NB1) partial += bsum[t];
    int t2 = t + 256;
    if (t2 < blockIdx.x && t2 < NB1) partial += bsum[t2];
    red[t] = partial;
    __syncthreads();
#pragma unroll
    for (int off = 128; off > 0; off >>= 1) {
        if (t < off) red[t] += red[t + off];
        __syncthreads();
    }
    int boff = red[0];
    int i = blockIdx.x * SCAN_B + t;
    if (i < N_NODES) row_ptr[i] += boff;
    if (i == 0) row_ptr[N_NODES] = N_EDGES;
}

// ---------------------------------------------------------------------------
// Fused dispatch: blocks [0, FILL_BLOCKS) scatter CSR cols (atomic-free via
// rank); blocks [FILL_BLOCKS, +INIT_BLOCKS) compute initial embeddings (bf16);
// one extra block pre-swizzles conv1_W into the gatherconv LDS layout:
//   Wsw4[j*128 + half*64 + (g*8+c)] = float4{ W[g*8+j][c*8 + half*4 .. +3] }
// (float4 units; j,half,g,c decompose the output index). This makes the
// gatherconv staging a straight linear copy and its phase-B reads 16B
// lane-stride (conflict-free; R4's 32B-stride layout measured 6.4M
// SQ_LDS_BANK_CONFLICT).
__global__ __launch_bounds__(256) void fill_init_kernel(
        const int2* __restrict__ edges,
        const int* __restrict__ rank,
        const int* __restrict__ rowp,
        int* __restrict__ col,
        const int* __restrict__ nodes,
        const float* __restrict__ features,
        const float* __restrict__ node_emb,
        const float* __restrict__ feat_W,
        const float* __restrict__ feat_b,
        unsigned short* __restrict__ embeds,
        const float* __restrict__ conv1_W,
        float* __restrict__ Wsw) {
    if (blockIdx.x < FILL_BLOCKS) {
        int t = blockIdx.x * 256 + threadIdx.x;
        int2 e = edges[t];
        col[rowp[e.y] + rank[t]] = e.x;
    } else if (blockIdx.x < FILL_BLOCKS + INIT_BLOCKS) {
        int tid = (blockIdx.x - FILL_BLOCKS) * 256 + threadIdx.x;
        int node = tid >> 6;
        int d = tid & 63;
        float acc = feat_b[d];
        const float* f = features + (size_t)node * 10;
        const float* w = feat_W + (size_t)d * 10;
#pragma unroll
        for (int j = 0; j < 10; ++j) acc += f[j] * w[j];
        embeds[tid] = f2bf(node_emb[(size_t)nodes[node] * D + d] + acc);
    } else {
        // pre-swizzle W: 1024 output float4, 4 per thread, coalesced writes
        int t = threadIdx.x;
#pragma unroll
        for (int q = 0; q < 4; ++q) {
            int v = t + 256 * q;              // output float4 index
            int j    = v >> 7;
            int rem  = v & 127;
            int half = rem >> 6;
            int L    = rem & 63;
            int g = L >> 3, c = L & 7;
            int src = (g * 8 + j) * 16 + c * 2 + half;   // source float4 index
            ((float4*)Wsw)[v] = ((const float4*)conv1_W)[src];
        }
    }
}

// ---------------------------------------------------------------------------
// FUSED gather + per-node conv. Keeps the 1-wave-per-node gather structure
// (R1: block-tile fusion lost 100K-wave concurrency, -21us).
//
// R4 -> R5 repairs (post-mortem driven):
//  * launch_bounds(256,8): R4's (256,6) capped occupancy at 81% while VGPR
//    was only 20 — the cap, not registers, throttled the latency-bound gather.
//  * W layout: two 16B-lane-stride b128 reads per j (wave reads 1KB
//    contiguous -> 2 lanes/bank = free) instead of one 32B-stride pair
//    (16-way conflict, 6.4M conflict-cycles measured).
//  * W staged from pre-swizzled Wsw: linear copy, no per-block index math.
//
// Phase A (gather, proven structure): x = emb[node] + sum emb[src];
// xor-reduce over g-bits -> lane (g,c) holds fp32 x[8c..8c+7].
// Phase B (conv): y[g*8+j] partials from chunk c, xor-reduce over c-bits,
// +bias, relu. !SCORE: lanes c==0 store bf16 row seg g. SCORE: in-wave
// cosine vs pattern, lane 0 stores score; y never materialized.
template <bool SCORE>
__global__ __launch_bounds__(256, 8) void gatherconv_kernel(
        const unsigned short* __restrict__ emb_in,
        const int* __restrict__ rowp,
        const int* __restrict__ col,
        const float* __restrict__ Wsw,
        const float* __restrict__ b,
        const float* __restrict__ pattern_emb,
        const int* __restrict__ pattern_id,
        unsigned short* __restrict__ emb_out,
        float* __restrict__ score_out) {
    __shared__ float4 Wl4[1024];    // 16 KB pre-swizzled fp32 W
    __shared__ float bl[64];
    __shared__ float ps[64];

    int t = threadIdx.x;

    // ---- Phase 0: linear W stage (4 coalesced float4 per thread) ----
#pragma unroll
    for (int q = 0; q < 4; ++q) {
        int v = t + 256 * q;
        Wl4[v] = ((const float4*)Wsw)[v];
    }
    if (t < 64) bl[t] = b[t];
    if (SCORE && t < 64) ps[t] = pattern_emb[(size_t)pattern_id[0] * D + t];
    __syncthreads();                          // only barrier; waves free after

    int lane = t & 63;
    int wv   = t >> 6;
    int node = blockIdx.x * 4 + wv;           // grid = 25000, exact
    int g = lane >> 3;                        // row-group / output-group 0..7
    int c = lane & 7;                         // uint4 chunk / k-chunk 0..7

    // ---- Phase A: gather ----
    int start = rowp[node];
    int end   = rowp[node + 1];

    float acc[8];
#pragma unroll
    for (int j = 0; j < 8; ++j) acc[j] = 0.f;
    if (g == 0) {                             // self term, counted once
        uint4 u = ((const uint4*)(emb_in + (size_t)node * D))[c];
        acc_bf8(acc, u);
    }

    for (int base = start; base < end; base += 32) {
        int nb = end - base; if (nb > 32) nb = 32;
        int idx = (lane < nb) ? col[base + lane] : 0;   // lanes 0..31, coalesced
#pragma unroll
        for (int r = 0; r < 4; ++r) {
            int s = r * 8 + g;                          // 0..31
            int src = __shfl(idx, s, 64);               // all lanes active
            if (s < nb) {                               // per-lane predication
                uint4 u = ((const uint4*)(emb_in + (size_t)src * D))[c];
                acc_bf8(acc, u);
            }
        }
    }
    // combine the 8 group partials (xor 8, 16, 32): lane (g,c) -> x[8c..8c+7]
#pragma unroll
    for (int m = 8; m <= 32; m <<= 1) {
#pragma unroll
        for (int j = 0; j < 8; ++j) acc[j] += __shfl_xor(acc[j], m, 64);
    }

    // ---- Phase B: per-node conv y = relu(x @ W^T + b) ----
    // Per j: two b128 reads at 16B lane-stride (1KB contiguous per wave).
    float y[8];
#pragma unroll
    for (int j = 0; j < 8; ++j) {
        float4 w0 = Wl4[j * 128 + lane];        // W[g*8+j][c*8+0..3]
        float4 w1 = Wl4[j * 128 + 64 + lane];   // W[g*8+j][c*8+4..7]
        y[j] = acc[0] * w0.x + acc[1] * w0.y + acc[2] * w0.z + acc[3] * w0.w
             + acc[4] * w1.x + acc[5] * w1.y + acc[6] * w1.z + acc[7] * w1.w;
    }
#pragma unroll
    for (int m = 1; m <= 4; m <<= 1) {        // reduce over k-chunks (c bits)
#pragma unroll
        for (int j = 0; j < 8; ++j) y[j] += __shfl_xor(y[j], m, 64);
    }
#pragma unroll
    for (int j = 0; j < 8; ++j) y[j] = fmaxf(y[j] + bl[g * 8 + j], 0.f);

    if (!SCORE) {
        if (c == 0) {                         // 8 lanes x 16 B = 128 B bf16 row
            uint4 p;
            p.x = pack2bf(y[0], y[1]);
            p.y = pack2bf(y[2], y[3]);
            p.z = pack2bf(y[4], y[5]);
            p.w = pack2bf(y[6], y[7]);
            ((uint4*)(emb_out + (size_t)node * D))[g] = p;
        }
    } else {
        float dot = 0.f, n2 = 0.f, pn = 0.f;
#pragma unroll
        for (int j = 0; j < 8; ++j) {
            float pk = ps[g * 8 + j];
            dot += y[j] * pk; n2 += y[j] * y[j]; pn += pk * pk;
        }
#pragma unroll
        for (int m = 8; m <= 32; m <<= 1) {   // reduce over output-groups (g bits)
            dot += __shfl_xor(dot, m, 64);
            n2  += __shfl_xor(n2,  m, 64);
            pn  += __shfl_xor(pn,  m, 64);
        }
        if (lane == 0)
            score_out[node] = dot / (fmaxf(sqrtf(n2), 1e-8f) * fmaxf(sqrtf(pn), 1e-8f));
    }
}

// ---------------------------------------------------------------------------
// Fallback path (atomic scatter, full fp32) if ws too small for CSR arrays.
__global__ void init_embeds_kernel(const int* __restrict__ nodes,
                                   const float* __restrict__ features,
                                   const float* __restrict__ node_emb,
                                   const float* __restrict__ feat_W,
                                   const float* __restrict__ feat_b,
                                   float* __restrict__ embeds) {
    int tid = blockIdx.x * blockDim.x + threadIdx.x;
    if (tid >= N_NODES * D) return;
    int node = tid >> 6;
    int d = tid & 63;
    float acc = feat_b[d];
    const float* f = features + (size_t)node * 10;
    const float* w = feat_W + (size_t)d * 10;
#pragma unroll
    for (int j = 0; j < 10; ++j) acc += f[j] * w[j];
    embeds[tid] = node_emb[(size_t)nodes[node] * D + d] + acc;
}

__global__ void scatter_add_kernel(const int* __restrict__ edges,
                                   const float* __restrict__ embeds,
                                   float* __restrict__ agg) {
    int tid = blockIdx.x * blockDim.x + threadIdx.x;
    int edge = tid >> 6;
    int lane = tid & 63;
    if (edge >= N_EDGES) return;
    int src = edges[2 * edge + 0];
    int dst = edges[2 * edge + 1];
    atomicAdd(&agg[(size_t)dst * D + lane], embeds[(size_t)src * D + lane]);
}

__global__ void conv_inplace_kernel(const float* __restrict__ agg,
                                    const float* __restrict__ W,
                                    const float* __restrict__ b,
                                    float* __restrict__ embeds) {
    __shared__ float Ws[D * 65];
    __shared__ float xs[4][D];
    for (int i = threadIdx.x; i < D * D; i += blockDim.x) {
        int d = i >> 6, k = i & 63;
        Ws[d * 65 + k] = W[i];
    }
    __syncthreads();
    int lane_d = threadIdx.x & 63;
    int local_n = threadIdx.x >> 6;
    float bias = b[lane_d];
    const int n_chunks = (N_NODES + 3) / 4;
    for (int chunk = blockIdx.x; chunk < n_chunks; chunk += gridDim.x) {
        int node = chunk * 4 + local_n;
        if (node < N_NODES) {
            size_t base = (size_t)node * D + lane_d;
            xs[local_n][lane_d] = embeds[base] + agg[base];
        }
        __syncthreads();
        if (node < N_NODES) {
            float acc = bias;
#pragma unroll
            for (int k = 0; k < D; ++k) acc += xs[local_n][k] * Ws[lane_d * 65 + k];
            embeds[(size_t)node * D + lane_d] = fmaxf(acc, 0.0f);
        }
        __syncthreads();
    }
}

__global__ void final_score_kernel(const float* __restrict__ embeds,
                                   const float* __restrict__ pattern_emb,
                                   const int* __restrict__ pattern_id,
                                   float* __restrict__ out) {
    int lane = threadIdx.x & 63;
    int wave = threadIdx.x >> 6;
    int node = blockIdx.x * 4 + wave;
    int pid = pattern_id[0];
    float p = pattern_emb[(size_t)pid * D + lane];
    float pn = p * p;
#pragma unroll
    for (int m = 32; m > 0; m >>= 1) pn += __shfl_xor(pn, m, 64);
    if (node < N_NODES) {
        float e = embeds[(size_t)node * D + lane];
        float dot = e * p;
        float n2 = e * e;
#pragma unroll
        for (int m = 32; m > 0; m >>= 1) {
            dot += __shfl_xor(dot, m, 64);
            n2  += __shfl_xor(n2, m, 64);
        }
        if (lane == 0) {
            float denom = fmaxf(sqrtf(n2), 1e-8f) * fmaxf(sqrtf(pn), 1e-8f);
            out[node] = dot / denom;
        }
    }
}

// ---------------------------------------------------------------------------
extern "C" void kernel_launch(void* const* d_in, const int* in_sizes, int n_in,
                              void* d_out, int out_size, void* d_ws, size_t ws_size,
                              hipStream_t stream) {
    const int*   nodes       = (const int*)d_in[0];
    const int*   edges       = (const int*)d_in[1];
    const float* features    = (const float*)d_in[2];
    const float* node_emb    = (const float*)d_in[3];
    const float* feat_W      = (const float*)d_in[4];
    const float* feat_b      = (const float*)d_in[5];
    const float* conv1_W     = (const float*)d_in[6];
    const float* conv1_b     = (const float*)d_in[7];
    const float* pattern_emb = (const float*)d_in[8];
    const int*   pattern_id  = (const int*)d_in[9];
    float* out = (float*)d_out;

    const size_t emb_f32_bytes = (size_t)N_NODES * D * sizeof(float);   // 25.6 MB
    const size_t emb_bf_bytes  = (size_t)N_NODES * D * 2;               // 12.8 MB
    auto align256 = [](size_t x) { return (x + 255) & ~(size_t)255; };

    size_t o_embA = 0;
    size_t o_embB = o_embA + align256(emb_bf_bytes);
    size_t o_col  = o_embB + align256(emb_bf_bytes);
    size_t o_rank = o_col  + align256((size_t)N_EDGES * 4);
    size_t o_row  = o_rank + align256((size_t)N_EDGES * 4);
    size_t o_deg  = o_row  + align256((size_t)(N_NODES + 1) * 4);
    size_t o_bsum = o_deg  + align256((size_t)N_NODES * 4);
    size_t o_wsw  = o_bsum + align256((size_t)NB1 * 4);
    size_t need   = o_wsw  + align256((size_t)D * D * sizeof(float));

    char* ws = (char*)d_ws;

    if (ws_size >= need) {
        unsigned short* embA = (unsigned short*)(ws + o_embA);
        unsigned short* embB = (unsigned short*)(ws + o_embB);
        int*   col  = (int*)(ws + o_col);
        int*   rank = (int*)(ws + o_rank);
        int*   rowp = (int*)(ws + o_row);
        int*   deg  = (int*)(ws + o_deg);
        int*   bsum = (int*)(ws + o_bsum);
        float* Wsw  = (float*)(ws + o_wsw);

        hipMemsetAsync(deg, 0, (size_t)N_NODES * 4, stream);
        hist_rank_kernel<<<FILL_BLOCKS, 256, 0, stream>>>((const int2*)edges, deg, rank);
        scan1_kernel<<<NB1, SCAN_B, 0, stream>>>(deg, rowp, bsum);
        scan23_kernel<<<NB1, SCAN_B, 0, stream>>>(rowp, bsum);
        fill_init_kernel<<<FILL_BLOCKS + INIT_BLOCKS + 1, 256, 0, stream>>>(
            (const int2*)edges, rank, rowp, col,
            nodes, features, node_emb, feat_W, feat_b, embA,
            conv1_W, Wsw);

        // iter 1: fused gather+conv -> embB (bf16)
        gatherconv_kernel<false><<<N_NODES / 4, 256, 0, stream>>>(
            embA, rowp, col, Wsw, conv1_b, pattern_emb, pattern_id, embB, nullptr);
        // iter 2: fused gather+conv+cosine score -> out (no y materialization)
        gatherconv_kernel<true><<<N_NODES / 4, 256, 0, stream>>>(
            embB, rowp, col, Wsw, conv1_b, pattern_emb, pattern_id, nullptr, out);
    } else {
        float* embeds = (float*)ws;
        float* agg = (float*)(ws + align256(emb_f32_bytes));
        init_embeds_kernel<<<(N_NODES * D + 255) / 256, 256, 0, stream>>>(
            nodes, features, node_emb, feat_W, feat_b, embeds);
        for (int it = 0; it < 2; ++it) {
            hipMemsetAsync(agg, 0, emb_f32_bytes, stream);
            long long total = (long long)N_EDGES * 64;
            scatter_add_kernel<<<(int)((total + 255) / 256), 256, 0, stream>>>(edges, embeds, agg);
            conv_inplace_kernel<<<2048, 256, 0, stream>>>(agg, conv1_W, conv1_b, embeds);
        }
        final_score_kernel<<<(N_NODES + 3) / 4, 256, 0, stream>>>(
            embeds, pattern_emb, pattern_id, out);
    }
}

// Round 6
// 260.989 us; speedup vs baseline: 1.2735x; 1.2220x over previous
//
#include <hip/hip_runtime.h>
#include <hip/hip_bf16.h>

#define N_NODES 100000
#define N_EDGES 800000
#define D 64
#define SCAN_B 256
#define NB1 ((N_NODES + SCAN_B - 1) / SCAN_B)   // 391 blocks
#define FILL_BLOCKS (N_EDGES / 256)             // 3125, exact
#define INIT_BLOCKS (N_NODES * D / 256)         // 25000, exact
#define CT 64                                   // conv tile: nodes per block
#define XS 68                                   // fp32 LDS row stride (bank-safe)
#define OS 72                                   // u16 LDS out row stride (144 B = 16B-aligned rows)

using bf16x8 = __attribute__((ext_vector_type(8))) short;
using f32x4  = __attribute__((ext_vector_type(4))) float;

// bf16 helpers: storage-only bf16 (embeds, x); all math fp32/MFMA-fp32-accum.
__device__ __forceinline__ unsigned short f2bf(float f) {
    union { float f; unsigned u; } v; v.f = f;
    unsigned r = v.u + 0x7fffu + ((v.u >> 16) & 1u);   // round-to-nearest-even
    return (unsigned short)(r >> 16);
}
__device__ __forceinline__ float bf2f(unsigned short u) {
    return __uint_as_float(((unsigned)u) << 16);
}
__device__ __forceinline__ void acc_bf8(float acc[8], uint4 u) {
    acc[0] += __uint_as_float(u.x << 16);
    acc[1] += __uint_as_float(u.x & 0xffff0000u);
    acc[2] += __uint_as_float(u.y << 16);
    acc[3] += __uint_as_float(u.y & 0xffff0000u);
    acc[4] += __uint_as_float(u.z << 16);
    acc[5] += __uint_as_float(u.z & 0xffff0000u);
    acc[6] += __uint_as_float(u.w << 16);
    acc[7] += __uint_as_float(u.w & 0xffff0000u);
}
__device__ __forceinline__ unsigned pack2bf(float a, float b) {
    return (unsigned)f2bf(a) | ((unsigned)f2bf(b) << 16);
}

// ---------------------------------------------------------------------------
// hist + rank: deg[dst]++, rank[e] = arrival order of edge e at its dst.
// NOTE (R2): cursor-atomic fill cost +40 us / +50 MB writebacks. Keep this.
__global__ __launch_bounds__(256) void hist_rank_kernel(
        const int2* __restrict__ edges,
        int* __restrict__ deg,
        int* __restrict__ rank) {
    int t = blockIdx.x * 256 + threadIdx.x;
    int2 e = edges[t];                      // grid exact: 3125*256 == N_EDGES
    rank[t] = atomicAdd(&deg[e.y], 1);
}

// ---------------------------------------------------------------------------
// scan1: block-local exclusive scan over deg -> row_ptr, emit block totals.
__global__ void scan1_kernel(const int* __restrict__ deg,
                             int* __restrict__ row_ptr,
                             int* __restrict__ bsum) {
    __shared__ int tmp[SCAN_B];
    int t = threadIdx.x;
    int i = blockIdx.x * SCAN_B + t;
    int v = (i < N_NODES) ? deg[i] : 0;
    tmp[t] = v;
    __syncthreads();
#pragma unroll
    for (int off = 1; off < SCAN_B; off <<= 1) {
        int a = (t >= off) ? tmp[t - off] : 0;
        __syncthreads();
        tmp[t] += a;
        __syncthreads();
    }
    if (i < N_NODES) row_ptr[i] = tmp[t] - v;   // exclusive
    if (t == SCAN_B - 1) bsum[blockIdx.x] = tmp[t];
}

// scan2+scan3 merged: each block reduce-sums bsum[0..blockIdx-1] (391 ints)
// and adds it to its 256 row_ptr entries.
__global__ void scan23_kernel(int* __restrict__ row_ptr,
                              const int* __restrict__ bsum) {
    __shared__ int red[SCAN_B];
    int t = threadIdx.x;
    int partial = 0;
    if (t < blockIdx.x && t < NB1) partial += bsum[t];
    int t2 = t + 256;
    if (t2 < blockIdx.x && t2 < NB1) partial += bsum[t2];
    red[t] = partial;
    __syncthreads();
#pragma unroll
    for (int off = 128; off > 0; off >>= 1) {
        if (t < off) red[t] += red[t + off];
        __syncthreads();
    }
    int boff = red[0];
    int i = blockIdx.x * SCAN_B + t;
    if (i < N_NODES) row_ptr[i] += boff;
    if (i == 0) row_ptr[N_NODES] = N_EDGES;
}

// ---------------------------------------------------------------------------
// Fused dispatch: blocks [0, FILL_BLOCKS) scatter CSR cols (atomic-free via
// rank); blocks [FILL_BLOCKS, +INIT_BLOCKS) compute initial embeddings
// (bf16); one extra block splits conv1_W into bf16 hi/lo (W ~= Whi + Wlo to
// fp32 precision) for the MFMA conv.
__global__ __launch_bounds__(256) void fill_init_kernel(
        const int2* __restrict__ edges,
        const int* __restrict__ rank,
        const int* __restrict__ rowp,
        int* __restrict__ col,
        const int* __restrict__ nodes,
        const float* __restrict__ features,
        const float* __restrict__ node_emb,
        const float* __restrict__ feat_W,
        const float* __restrict__ feat_b,
        unsigned short* __restrict__ embeds,
        const float* __restrict__ conv1_W,
        unsigned short* __restrict__ Whi,
        unsigned short* __restrict__ Wlo) {
    if (blockIdx.x < FILL_BLOCKS) {
        int t = blockIdx.x * 256 + threadIdx.x;
        int2 e = edges[t];
        col[rowp[e.y] + rank[t]] = e.x;
    } else if (blockIdx.x < FILL_BLOCKS + INIT_BLOCKS) {
        int tid = (blockIdx.x - FILL_BLOCKS) * 256 + threadIdx.x;
        int node = tid >> 6;
        int d = tid & 63;
        float acc = feat_b[d];
        const float* f = features + (size_t)node * 10;
        const float* w = feat_W + (size_t)d * 10;
#pragma unroll
        for (int j = 0; j < 10; ++j) acc += f[j] * w[j];
        embeds[tid] = f2bf(node_emb[(size_t)nodes[node] * D + d] + acc);
    } else {
        // split W: 4096 elems, 16 per thread, coalesced
        int t = threadIdx.x;
#pragma unroll
        for (int j = 0; j < 16; ++j) {
            int i = t + 256 * j;
            float w = conv1_W[i];
            unsigned short hi = f2bf(w);
            Whi[i] = hi;
            Wlo[i] = f2bf(w - bf2f(hi));
        }
    }
}

// ---------------------------------------------------------------------------
// x[node] = emb_in[node] + sum_{src} emb_in[src]   (emb bf16, acc fp32,
// OUTPUT bf16). R6: TWO nodes per wave — the gather is concurrency-limited
// (R5 data: 47 MB @ ~1 TB/s, 16% HBM, full wave occupancy), so double the
// dependent chains per wave. CSR contiguity means nodes 2b,2b+1 share one
// contiguous col range [rowp[2b], rowp[2b+2]) split at rowp[2b+1]: one
// 64-lane coalesced col load covers both. Self terms: group 0 -> node0,
// group 1 -> node1. Per-edge accumulate is predicated into a0/a1 by
// (pos < split). xor-reduce over g-bits sums all groups for BOTH accs;
// groups 0/1 write the two adjacent output rows (256 B contiguous).
// VGPR ~48 < 64 cap -> 8 waves/SIMD holds.
// DO NOT fuse with conv (R1: -21us; R4/R5: 25K-block W-stage prologue +
// per-node LDS traffic = +42us even conflict-free).
__global__ __launch_bounds__(256, 8) void gather_x_kernel(
        const unsigned short* __restrict__ emb_in,
        const int* __restrict__ rowp,
        const int* __restrict__ col,
        unsigned short* __restrict__ x_out) {
    int lane = threadIdx.x & 63;
    int wv   = threadIdx.x >> 6;
    int n0   = blockIdx.x * 8 + wv * 2;      // grid = 12500, exact
    int g = lane >> 3;                        // row-group 0..7
    int c = lane & 7;                         // uint4 chunk 0..7

    // rowp[n0], rowp[n0+1], rowp[n0+2]: one lane-load + broadcast
    int rp = (lane < 3) ? rowp[n0 + lane] : 0;
    int start = __shfl(rp, 0, 64);
    int split = __shfl(rp, 1, 64);
    int end   = __shfl(rp, 2, 64);

    float a0[8], a1[8];
#pragma unroll
    for (int j = 0; j < 8; ++j) { a0[j] = 0.f; a1[j] = 0.f; }

    if (g == 0) {                             // self term node0, counted once
        uint4 u = ((const uint4*)(emb_in + (size_t)n0 * D))[c];
        acc_bf8(a0, u);
    } else if (g == 1) {                      // self term node1, counted once
        uint4 u = ((const uint4*)(emb_in + (size_t)(n0 + 1) * D))[c];
        acc_bf8(a1, u);
    }

    for (int base = start; base < end; base += 64) {
        int nb = end - base; if (nb > 64) nb = 64;
        int idx = (lane < nb) ? col[base + lane] : 0;   // 64 lanes, coalesced
#pragma unroll
        for (int r = 0; r < 8; ++r) {
            int s = r * 8 + g;                          // 0..63
            int src = __shfl(idx, s, 64);               // all lanes active
            if (s < nb) {                               // per-lane predication
                uint4 u = ((const uint4*)(emb_in + (size_t)src * D))[c];
                if (base + s < split) acc_bf8(a0, u);
                else                  acc_bf8(a1, u);
            }
        }
    }

    // combine the 8 group partials (xor 8, 16, 32) for both accumulators
#pragma unroll
    for (int m = 8; m <= 32; m <<= 1) {
#pragma unroll
        for (int j = 0; j < 8; ++j) {
            a0[j] += __shfl_xor(a0[j], m, 64);
            a1[j] += __shfl_xor(a1[j], m, 64);
        }
    }

    if (g == 0) {                             // node0 row: 8 lanes x 16 B
        uint4 p;
        p.x = pack2bf(a0[0], a0[1]);
        p.y = pack2bf(a0[2], a0[3]);
        p.z = pack2bf(a0[4], a0[5]);
        p.w = pack2bf(a0[6], a0[7]);
        ((uint4*)(x_out + (size_t)n0 * D))[c] = p;
    } else if (g == 1) {                      // node1 row (adjacent 128 B)
        uint4 p;
        p.x = pack2bf(a1[0], a1[1]);
        p.y = pack2bf(a1[2], a1[3]);
        p.z = pack2bf(a1[4], a1[5]);
        p.w = pack2bf(a1[6], a1[7]);
        ((uint4*)(x_out + (size_t)(n0 + 1) * D))[c] = p;
    }
}

// ---------------------------------------------------------------------------
// MFMA conv: y = relu(x @ W^T + b) via mfma_f32_16x16x32_bf16, W in bf16
// hi/lo split (2 MFMAs per k-step -> fp32-accurate W). No X/W LDS staging:
// A-frags load straight from global x (lane: row=lane&15, k=(lane>>4)*8+j),
// B-frags from Whi/Wlo rows — W is 8 KB x2, L1/L2-hot across all blocks.
// C/D layout (m89-verified): col=lane&15, row=(lane>>4)*4+reg.
// 4 waves x 16 nodes = 64 nodes/block. Verified passing in R2/R3.
// !SCORE: bf16 pack via LDS transpose -> coalesced uint4 stores.
// SCORE: fp32 y via LDS, wave0 per-node cosine vs pattern -> score_out.
template <bool SCORE>
__global__ __launch_bounds__(256) void conv_mfma_kernel(
        const unsigned short* __restrict__ x,
        const unsigned short* __restrict__ Whi,
        const unsigned short* __restrict__ Wlo,
        const float* __restrict__ b,
        const float* __restrict__ pattern_emb,
        const int* __restrict__ pattern_id,
        unsigned short* __restrict__ emb_out,
        float* __restrict__ score_out) {
    __shared__ union {
        unsigned short Os[CT][OS];   // 9216 B  (!SCORE epilogue)
        float Ys[CT][XS];            // 17408 B (SCORE epilogue)
    } u;
    __shared__ float ps[D];

    int t = threadIdx.x;
    int lane = t & 63;
    int wv = t >> 6;                          // wave 0..3
    int base = blockIdx.x * CT;
    int nodebase = base + wv * 16;
    int row16 = lane & 15;                    // A-row / B-col within tile
    int kq = lane >> 4;                       // k-quarter 0..3

    if (SCORE && t < D) ps[t] = pattern_emb[(size_t)pattern_id[0] * D + t];

    // A fragments (k-steps 0,1). Rows >= N_NODES (last block tail) read
    // in-workspace garbage; their outputs are predicated off below.
    const bf16x8* xp = (const bf16x8*)(x + (size_t)(nodebase + row16) * D + kq * 8);
    bf16x8 a0 = xp[0];                        // k = kq*8 .. +7
    bf16x8 a1 = xp[4];                        // k = 32 + kq*8 .. +7

    f32x4 acc[4] = {};
    float bj[4];
#pragma unroll
    for (int tc = 0; tc < 4; ++tc) {
        int o = tc * 16 + row16;              // output dim for this lane/tile
        bj[tc] = b[o];
        const bf16x8* wh = (const bf16x8*)(Whi + (size_t)o * D + kq * 8);
        const bf16x8* wl = (const bf16x8*)(Wlo + (size_t)o * D + kq * 8);
        acc[tc] = __builtin_amdgcn_mfma_f32_16x16x32_bf16(a0, wh[0], acc[tc], 0, 0, 0);
        acc[tc] = __builtin_amdgcn_mfma_f32_16x16x32_bf16(a1, wh[4], acc[tc], 0, 0, 0);
        acc[tc] = __builtin_amdgcn_mfma_f32_16x16x32_bf16(a0, wl[0], acc[tc], 0, 0, 0);
        acc[tc] = __builtin_amdgcn_mfma_f32_16x16x32_bf16(a1, wl[4], acc[tc], 0, 0, 0);
    }

    if (!SCORE) {
#pragma unroll
        for (int tc = 0; tc < 4; ++tc)
#pragma unroll
            for (int r = 0; r < 4; ++r)
                u.Os[wv * 16 + kq * 4 + r][tc * 16 + row16] =
                    f2bf(fmaxf(acc[tc][r] + bj[tc], 0.f));
        __syncthreads();
#pragma unroll
        for (int q = 0; q < 2; ++q) {
            int idx = t + q * 256;            // 0..511: 64 rows x 8 uint4 segs
            int r = idx >> 3, seg = idx & 7;
            int node = base + r;
            if (node < N_NODES)
                ((uint4*)(emb_out + (size_t)node * D))[seg] = *((const uint4*)&u.Os[r][8 * seg]);
        }
    } else {
#pragma unroll
        for (int tc = 0; tc < 4; ++tc)
#pragma unroll
            for (int r = 0; r < 4; ++r)
                u.Ys[wv * 16 + kq * 4 + r][tc * 16 + row16] = fmaxf(acc[tc][r] + bj[tc], 0.f);
        __syncthreads();
        if (t < CT) {                         // wave 0: one lane per node
            float dot = 0.f, n2 = 0.f, pn = 0.f;
#pragma unroll 8
            for (int k = 0; k < D; ++k) {
                float yk = u.Ys[t][k];
                float pk = ps[k];
                dot += yk * pk; n2 += yk * yk; pn += pk * pk;
            }
            int node = base + t;
            if (node < N_NODES)
                score_out[node] = dot / (fmaxf(sqrtf(n2), 1e-8f) * fmaxf(sqrtf(pn), 1e-8f));
        }
    }
}

// ---------------------------------------------------------------------------
// Fallback path (atomic scatter, full fp32) if ws too small for CSR arrays.
__global__ void init_embeds_kernel(const int* __restrict__ nodes,
                                   const float* __restrict__ features,
                                   const float* __restrict__ node_emb,
                                   const float* __restrict__ feat_W,
                                   const float* __restrict__ feat_b,
                                   float* __restrict__ embeds) {
    int tid = blockIdx.x * blockDim.x + threadIdx.x;
    if (tid >= N_NODES * D) return;
    int node = tid >> 6;
    int d = tid & 63;
    float acc = feat_b[d];
    const float* f = features + (size_t)node * 10;
    const float* w = feat_W + (size_t)d * 10;
#pragma unroll
    for (int j = 0; j < 10; ++j) acc += f[j] * w[j];
    embeds[tid] = node_emb[(size_t)nodes[node] * D + d] + acc;
}

__global__ void scatter_add_kernel(const int* __restrict__ edges,
                                   const float* __restrict__ embeds,
                                   float* __restrict__ agg) {
    int tid = blockIdx.x * blockDim.x + threadIdx.x;
    int edge = tid >> 6;
    int lane = tid & 63;
    if (edge >= N_EDGES) return;
    int src = edges[2 * edge + 0];
    int dst = edges[2 * edge + 1];
    atomicAdd(&agg[(size_t)dst * D + lane], embeds[(size_t)src * D + lane]);
}

__global__ void conv_inplace_kernel(const float* __restrict__ agg,
                                    const float* __restrict__ W,
                                    const float* __restrict__ b,
                                    float* __restrict__ embeds) {
    __shared__ float Ws[D * 65];
    __shared__ float xs[4][D];
    for (int i = threadIdx.x; i < D * D; i += blockDim.x) {
        int d = i >> 6, k = i & 63;
        Ws[d * 65 + k] = W[i];
    }
    __syncthreads();
    int lane_d = threadIdx.x & 63;
    int local_n = threadIdx.x >> 6;
    float bias = b[lane_d];
    const int n_chunks = (N_NODES + 3) / 4;
    for (int chunk = blockIdx.x; chunk < n_chunks; chunk += gridDim.x) {
        int node = chunk * 4 + local_n;
        if (node < N_NODES) {
            size_t base = (size_t)node * D + lane_d;
            xs[local_n][lane_d] = embeds[base] + agg[base];
        }
        __syncthreads();
        if (node < N_NODES) {
            float acc = bias;
#pragma unroll
            for (int k = 0; k < D; ++k) acc += xs[local_n][k] * Ws[lane_d * 65 + k];
            embeds[(size_t)node * D + lane_d] = fmaxf(acc, 0.0f);
        }
        __syncthreads();
    }
}

__global__ void final_score_kernel(const float* __restrict__ embeds,
                                   const float* __restrict__ pattern_emb,
                                   const int* __restrict__ pattern_id,
                                   float* __restrict__ out) {
    int lane = threadIdx.x & 63;
    int wave = threadIdx.x >> 6;
    int node = blockIdx.x * 4 + wave;
    int pid = pattern_id[0];
    float p = pattern_emb[(size_t)pid * D + lane];
    float pn = p * p;
#pragma unroll
    for (int m = 32; m > 0; m >>= 1) pn += __shfl_xor(pn, m, 64);
    if (node < N_NODES) {
        float e = embeds[(size_t)node * D + lane];
        float dot = e * p;
        float n2 = e * e;
#pragma unroll
        for (int m = 32; m > 0; m >>= 1) {
            dot += __shfl_xor(dot, m, 64);
            n2  += __shfl_xor(n2, m, 64);
        }
        if (lane == 0) {
            float denom = fmaxf(sqrtf(n2), 1e-8f) * fmaxf(sqrtf(pn), 1e-8f);
            out[node] = dot / denom;
        }
    }
}

// ---------------------------------------------------------------------------
extern "C" void kernel_launch(void* const* d_in, const int* in_sizes, int n_in,
                              void* d_out, int out_size, void* d_ws, size_t ws_size,
                              hipStream_t stream) {
    const int*   nodes       = (const int*)d_in[0];
    const int*   edges       = (const int*)d_in[1];
    const float* features    = (const float*)d_in[2];
    const float* node_emb    = (const float*)d_in[3];
    const float* feat_W      = (const float*)d_in[4];
    const float* feat_b      = (const float*)d_in[5];
    const float* conv1_W     = (const float*)d_in[6];
    const float* conv1_b     = (const float*)d_in[7];
    const float* pattern_emb = (const float*)d_in[8];
    const int*   pattern_id  = (const int*)d_in[9];
    float* out = (float*)d_out;

    const size_t emb_f32_bytes = (size_t)N_NODES * D * sizeof(float);   // 25.6 MB
    const size_t emb_bf_bytes  = (size_t)N_NODES * D * 2;               // 12.8 MB
    auto align256 = [](size_t x) { return (x + 255) & ~(size_t)255; };

    size_t o_embA = 0;
    size_t o_embB = o_embA + align256(emb_bf_bytes);
    size_t o_xbuf = o_embB + align256(emb_bf_bytes);
    size_t o_col  = o_xbuf + align256(emb_bf_bytes);
    size_t o_rank = o_col  + align256((size_t)N_EDGES * 4);
    size_t o_row  = o_rank + align256((size_t)N_EDGES * 4);
    size_t o_deg  = o_row  + align256((size_t)(N_NODES + 1) * 4);
    size_t o_bsum = o_deg  + align256((size_t)N_NODES * 4);
    size_t o_whi  = o_bsum + align256((size_t)NB1 * 4);
    size_t o_wlo  = o_whi  + align256((size_t)D * D * 2);
    size_t need   = o_wlo  + align256((size_t)D * D * 2);

    char* ws = (char*)d_ws;

    if (ws_size >= need) {
        unsigned short* embA = (unsigned short*)(ws + o_embA);
        unsigned short* embB = (unsigned short*)(ws + o_embB);
        unsigned short* xbuf = (unsigned short*)(ws + o_xbuf);
        int*   col  = (int*)(ws + o_col);
        int*   rank = (int*)(ws + o_rank);
        int*   rowp = (int*)(ws + o_row);
        int*   deg  = (int*)(ws + o_deg);
        int*   bsum = (int*)(ws + o_bsum);
        unsigned short* Whi = (unsigned short*)(ws + o_whi);
        unsigned short* Wlo = (unsigned short*)(ws + o_wlo);

        hipMemsetAsync(deg, 0, (size_t)N_NODES * 4, stream);
        hist_rank_kernel<<<FILL_BLOCKS, 256, 0, stream>>>((const int2*)edges, deg, rank);
        scan1_kernel<<<NB1, SCAN_B, 0, stream>>>(deg, rowp, bsum);
        scan23_kernel<<<NB1, SCAN_B, 0, stream>>>(rowp, bsum);
        fill_init_kernel<<<FILL_BLOCKS + INIT_BLOCKS + 1, 256, 0, stream>>>(
            (const int2*)edges, rank, rowp, col,
            nodes, features, node_emb, feat_W, feat_b, embA,
            conv1_W, Whi, Wlo);

        const int conv_grid = (N_NODES + CT - 1) / CT;   // 1563

        // iter 1: gather(2 nodes/wave) + MFMA conv -> embB (bf16)
        gather_x_kernel<<<N_NODES / 8, 256, 0, stream>>>(embA, rowp, col, xbuf);
        conv_mfma_kernel<false><<<conv_grid, 256, 0, stream>>>(
            xbuf, Whi, Wlo, conv1_b, pattern_emb, pattern_id, embB, nullptr);
        // iter 2: gather + MFMA conv fused with cosine score -> out
        gather_x_kernel<<<N_NODES / 8, 256, 0, stream>>>(embB, rowp, col, xbuf);
        conv_mfma_kernel<true><<<conv_grid, 256, 0, stream>>>(
            xbuf, Whi, Wlo, conv1_b, pattern_emb, pattern_id, nullptr, out);
    } else {
        float* embeds = (float*)ws;
        float* agg = (float*)(ws + align256(emb_f32_bytes));
        init_embeds_kernel<<<(N_NODES * D + 255) / 256, 256, 0, stream>>>(
            nodes, features, node_emb, feat_W, feat_b, embeds);
        for (int it = 0; it < 2; ++it) {
            hipMemsetAsync(agg, 0, emb_f32_bytes, stream);
            long long total = (long long)N_EDGES * 64;
            scatter_add_kernel<<<(int)((total + 255) / 256), 256, 0, stream>>>(edges, embeds, agg);
            conv_inplace_kernel<<<2048, 256, 0, stream>>>(agg, conv1_W, conv1_b, embeds);
        }
        final_score_kernel<<<(N_NODES + 3) / 4, 256, 0, stream>>>(
            embeds, pattern_emb, pattern_id, out);
    }
}